// Round 9
// baseline (455.786 us; speedup 1.0000x reference)
//
#include <hip/hip_runtime.h>
#include <hip/hip_bf16.h>
#include <hip/hip_fp16.h>

// Problem constants
#define BATCH 64
#define C_IN 16
#define T0 8192
#define T1 4096   // after pool1
#define T2 2048   // after pool2 (nodes per batch)
#define N_NODES (BATCH * T2)   // 131072
#define NHALF (N_NODES / 2)    // source-slice boundary (4MB fp8 rows per slice)
#define HID 64
#define NOUT 10

// Coarse-bucket edge partition parameters
#define NCB 256
#define CB_SHIFT 9
#define CB_TGT 512
#define RCAP 9216
#define PC_EDGES 2048
#define PC_CAP 28

// fp8 message-table scale
#define MSG_SCALE 64.0f
#define MSG_ISCALE (1.0f / 64.0f)

typedef __fp16 half8 __attribute__((ext_vector_type(8)));
typedef float floatx4 __attribute__((ext_vector_type(4)));

#define F8(w, s) __builtin_amdgcn_cvt_f32_fp8((int)(w), (s))

// ---------------- conv1: [64,16,8192] -> relu -> pool2 -> h1 [64,16,4096]
__global__ __launch_bounds__(256) void conv1_kernel(const float* __restrict__ x,
    const float* __restrict__ w, const float* __restrict__ bias,
    float* __restrict__ h1) {
  __shared__ float xs[16 * 520];
  int b = blockIdx.x >> 4;
  int tp0 = (blockIdx.x & 15) * 256;
  int t_base = tp0 * 2 - 2;
  const float* xb = x + (size_t)b * C_IN * T0;
  for (int idx = threadIdx.x; idx < 16 * 516; idx += 256) {
    int ci = idx / 516;
    int off = idx - ci * 516;
    int gt = t_base + off;
    float v = 0.f;
    if (gt >= 0 && gt < T0) v = xb[ci * T0 + gt];
    xs[ci * 520 + off] = v;
  }
  __syncthreads();
  int tp = threadIdx.x;
  float acc0[16], acc1[16];
#pragma unroll
  for (int co = 0; co < 16; ++co) { acc0[co] = 0.f; acc1[co] = 0.f; }
#pragma unroll 4
  for (int ci = 0; ci < 16; ++ci) {
    float xv[6];
#pragma unroll
    for (int k = 0; k < 6; ++k) xv[k] = xs[ci * 520 + 2 * tp + k];
#pragma unroll
    for (int co = 0; co < 16; ++co) {
#pragma unroll
      for (int k = 0; k < 5; ++k) {
        float wv = w[(co * 16 + ci) * 5 + k];
        acc0[co] += xv[k] * wv;
        acc1[co] += xv[k + 1] * wv;
      }
    }
  }
#pragma unroll
  for (int co = 0; co < 16; ++co) {
    float v = fmaxf(acc0[co], acc1[co]) + bias[co];
    v = fmaxf(v, 0.f);
    h1[((size_t)b * 16 + co) * T1 + tp0 + tp] = v;
  }
}

// ---------------- conv2: h1 [64,16,4096] -> relu -> pool2 -> feat fp16 [131072,32]
__global__ __launch_bounds__(256) void conv2_kernel(const float* __restrict__ h1,
    const float* __restrict__ w, const float* __restrict__ bias,
    __fp16* __restrict__ feat) {
  __shared__ float xs[16 * 520];
  int b = blockIdx.x >> 3;
  int tp0 = (blockIdx.x & 7) * 256;
  int t_base = tp0 * 2 - 2;
  const float* xb = h1 + (size_t)b * 16 * T1;
  for (int idx = threadIdx.x; idx < 16 * 516; idx += 256) {
    int ci = idx / 516;
    int off = idx - ci * 516;
    int gt = t_base + off;
    float v = 0.f;
    if (gt >= 0 && gt < T1) v = xb[ci * T1 + gt];
    xs[ci * 520 + off] = v;
  }
  __syncthreads();
  int tp = threadIdx.x;
  float acc0[32], acc1[32];
#pragma unroll
  for (int co = 0; co < 32; ++co) { acc0[co] = 0.f; acc1[co] = 0.f; }
#pragma unroll 2
  for (int ci = 0; ci < 16; ++ci) {
    float xv[6];
#pragma unroll
    for (int k = 0; k < 6; ++k) xv[k] = xs[ci * 520 + 2 * tp + k];
#pragma unroll
    for (int co = 0; co < 32; ++co) {
#pragma unroll
      for (int k = 0; k < 5; ++k) {
        float wv = w[(co * 16 + ci) * 5 + k];
        acc0[co] += xv[k] * wv;
        acc1[co] += xv[k + 1] * wv;
      }
    }
  }
  half8 hres[4];
#pragma unroll
  for (int co = 0; co < 32; ++co) {
    float v = fmaxf(acc0[co], acc1[co]) + bias[co];
    hres[co >> 3][co & 7] = (__fp16)fmaxf(v, 0.f);
  }
  size_t nrow = ((size_t)b * T2 + tp0 + tp) * 32;
  half8* f8 = (half8*)(feat + nrow);
#pragma unroll
  for (int j = 0; j < 4; ++j) f8[j] = hres[j];
}

// ---------------- pass C: partition edges into coarse-bucket regions via LDS staging
__global__ __launch_bounds__(256) void partition_pairs(const int* __restrict__ ei, int E,
    int* __restrict__ rcnt, int2* __restrict__ gpairs) {
  __shared__ int lcnt[NCB];
  __shared__ int lrow[NCB * PC_CAP];
  __shared__ int lcol[NCB * PC_CAP];
  if (threadIdx.x < NCB) lcnt[threadIdx.x] = 0;
  __syncthreads();
  int e0 = blockIdx.x * PC_EDGES;
#pragma unroll
  for (int j = 0; j < PC_EDGES / 256; ++j) {
    int e = e0 + j * 256 + threadIdx.x;
    if (e < E) {
      int r = ei[e];
      int c = ei[E + e];
      int cb = c >> CB_SHIFT;
      int slot = atomicAdd(&lcnt[cb], 1);
      if (slot < PC_CAP) {
        lrow[cb * PC_CAP + slot] = r;
        lcol[cb * PC_CAP + slot] = c;
      } else {
        int pos = atomicAdd(&rcnt[cb], 1);
        if (pos < RCAP) gpairs[(size_t)cb * RCAP + pos] = make_int2(r, c);
      }
    }
  }
  __syncthreads();
  int t = threadIdx.x;
  if (t < NCB) {
    int n = lcnt[t];
    if (n > PC_CAP) n = PC_CAP;
    if (n > 0) {
      int base = atomicAdd(&rcnt[t], n);
      int2* dst = gpairs + (size_t)t * RCAP;
      for (int k = 0; k < n; ++k) {
        int p = base + k;
        if (p < RCAP) dst[p] = make_int2(lrow[t * PC_CAP + k], lcol[t * PC_CAP + k]);
      }
    }
  }
}

// ---------------- pass D: per coarse bucket, build CSR split by source half + dis
__global__ __launch_bounds__(512) void build_csr(const int2* __restrict__ gpairs,
    const int* __restrict__ rcnt, int* __restrict__ ebuf,
    int* __restrict__ estart, int* __restrict__ ecnt, int* __restrict__ ssplit,
    float* __restrict__ dis) {
  __shared__ int deg0[CB_TGT];
  __shared__ int deg1[CB_TGT];
  __shared__ int sc[CB_TGT];
  __shared__ int cur0[CB_TGT];
  __shared__ int cur1[CB_TGT];
  int b = blockIdx.x;
  int t = threadIdx.x;
  deg0[t] = 0; deg1[t] = 0; cur0[t] = 0; cur1[t] = 0;
  __syncthreads();
  int m = rcnt[b];
  if (m > RCAP) m = RCAP;
  const int2* reg = gpairs + (size_t)b * RCAP;
  for (int k = t; k < m; k += 512) {
    int2 p = reg[k];
    int lc = p.y - (b << CB_SHIFT);
    if (p.x < NHALF) atomicAdd(&deg0[lc], 1);
    else atomicAdd(&deg1[lc], 1);
  }
  __syncthreads();
  int d0 = deg0[t];
  int dtot = d0 + deg1[t];
  sc[t] = dtot;
  __syncthreads();
  for (int s = 1; s < CB_TGT; s <<= 1) {
    int v = (t >= s) ? sc[t - s] : 0;
    __syncthreads();
    sc[t] += v;
    __syncthreads();
  }
  sc[t] -= dtot;
  __syncthreads();
  int gi = (b << CB_SHIFT) + t;
  int base = b * RCAP;
  estart[gi] = base + sc[t];
  ecnt[gi] = dtot;
  ssplit[gi] = d0;
  dis[gi] = rsqrtf((float)dtot + 1.0f);
  for (int k = t; k < m; k += 512) {
    int2 p = reg[k];
    int lc = p.y - (b << CB_SHIFT);
    int pos;
    if (p.x < NHALF) pos = base + sc[lc] + atomicAdd(&cur0[lc], 1);
    else pos = base + sc[lc] + deg0[lc] + atomicAdd(&cur1[lc], 1);
    ebuf[pos] = p.x;
  }
}

// ---------------- MFMA node GEMM, K=32: xw[n] = fp8( 64 * dis[n] * (feat[n] @ W) )
__global__ __launch_bounds__(256) void gemm1_mfma(const __fp16* __restrict__ in,
    const float* __restrict__ W, const float* __restrict__ dis,
    unsigned char* __restrict__ out, int NT) {
  int lane = threadIdx.x & 63;
  int m = lane & 15;
  int q = lane >> 4;
  half8 bf[4];
#pragma unroll
  for (int t = 0; t < 4; ++t)
#pragma unroll
    for (int j = 0; j < 8; ++j)
      bf[t][j] = (__fp16)W[(q * 8 + j) * 64 + t * 16 + m];
  int wid = (int)((blockIdx.x * blockDim.x + threadIdx.x) >> 6);
  int nwaves = (gridDim.x * blockDim.x) >> 6;
  for (int tile = wid; tile < NT; tile += nwaves) {
    int base = tile * 16;
    half8 a = *(const half8*)(in + (size_t)(base + m) * 32 + q * 8);
    float d[4];
#pragma unroll
    for (int r = 0; r < 4; ++r) d[r] = dis[base + q * 4 + r] * MSG_SCALE;
#pragma unroll
    for (int t = 0; t < 4; ++t) {
      floatx4 acc = {0.f, 0.f, 0.f, 0.f};
      acc = __builtin_amdgcn_mfma_f32_16x16x32_f16(a, bf[t], acc, 0, 0, 0);
#pragma unroll
      for (int r = 0; r < 4; ++r) {
        float v = acc[r] * d[r];
        int pk = __builtin_amdgcn_cvt_pk_fp8_f32(v, v, 0, false);
        out[(size_t)(base + q * 4 + r) * 64 + t * 16 + m] = (unsigned char)(pk & 0xFF);
      }
    }
  }
}

// ---------------- MFMA node GEMM, K=64: xw2[n] = fp8( 64 * dis[n] * (g1[n] @ W) )
__global__ __launch_bounds__(256) void gemm2_mfma(const __fp16* __restrict__ in,
    const float* __restrict__ W, const float* __restrict__ dis,
    unsigned char* __restrict__ out, int NT) {
  int lane = threadIdx.x & 63;
  int m = lane & 15;
  int q = lane >> 4;
  half8 bf[4][2];
#pragma unroll
  for (int t = 0; t < 4; ++t)
#pragma unroll
    for (int s = 0; s < 2; ++s)
#pragma unroll
      for (int j = 0; j < 8; ++j)
        bf[t][s][j] = (__fp16)W[(s * 32 + q * 8 + j) * 64 + t * 16 + m];
  int wid = (int)((blockIdx.x * blockDim.x + threadIdx.x) >> 6);
  int nwaves = (gridDim.x * blockDim.x) >> 6;
  for (int tile = wid; tile < NT; tile += nwaves) {
    int base = tile * 16;
    half8 a0 = *(const half8*)(in + (size_t)(base + m) * 64 + q * 8);
    half8 a1 = *(const half8*)(in + (size_t)(base + m) * 64 + 32 + q * 8);
    float d[4];
#pragma unroll
    for (int r = 0; r < 4; ++r) d[r] = dis[base + q * 4 + r] * MSG_SCALE;
#pragma unroll
    for (int t = 0; t < 4; ++t) {
      floatx4 acc = {0.f, 0.f, 0.f, 0.f};
      acc = __builtin_amdgcn_mfma_f32_16x16x32_f16(a0, bf[t][0], acc, 0, 0, 0);
      acc = __builtin_amdgcn_mfma_f32_16x16x32_f16(a1, bf[t][1], acc, 0, 0, 0);
#pragma unroll
      for (int r = 0; r < 4; ++r) {
        float v = acc[r] * d[r];
        int pk = __builtin_amdgcn_cvt_pk_fp8_f32(v, v, 0, false);
        out[(size_t)(base + q * 4 + r) * 64 + t * 16 + m] = (unsigned char)(pk & 0xFF);
      }
    }
  }
}

// ---------------- aggregate phase A: sum slice-0 sources (4MB L2-resident table
// slice), write raw partial sums fp32 (nontemporal - don't evict the slice).
__global__ __launch_bounds__(256) void agg_partial(const unsigned char* __restrict__ tab,
    const int* __restrict__ ebuf, const int* __restrict__ estart,
    const int* __restrict__ ssplit, float* __restrict__ part, int N) {
  int lane = threadIdx.x & 63;
  int es = lane >> 3;
  int ch = lane & 7;
  int wid = (int)((blockIdx.x * blockDim.x + threadIdx.x) >> 6);
  int nwaves = (gridDim.x * blockDim.x) >> 6;
  for (int i = wid; i < N; i += nwaves) {
    int st = estart[i];
    int c = ssplit[i];
    const int* eb = ebuf + st;
    float a[8];
#pragma unroll
    for (int j = 0; j < 8; ++j) a[j] = 0.f;
    int s = 0;
    for (; s + 16 <= c; s += 16) {
      int r0 = __builtin_nontemporal_load(eb + s + es);
      int r1 = __builtin_nontemporal_load(eb + s + 8 + es);
      uint2 h0 = *(const uint2*)(tab + (size_t)r0 * 64 + ch * 8);
      uint2 h1 = *(const uint2*)(tab + (size_t)r1 * 64 + ch * 8);
      a[0] += F8(h0.x, 0) + F8(h1.x, 0);
      a[1] += F8(h0.x, 1) + F8(h1.x, 1);
      a[2] += F8(h0.x, 2) + F8(h1.x, 2);
      a[3] += F8(h0.x, 3) + F8(h1.x, 3);
      a[4] += F8(h0.y, 0) + F8(h1.y, 0);
      a[5] += F8(h0.y, 1) + F8(h1.y, 1);
      a[6] += F8(h0.y, 2) + F8(h1.y, 2);
      a[7] += F8(h0.y, 3) + F8(h1.y, 3);
    }
    for (; s < c; s += 8) {
      bool ok = (s + es) < c;
      int r = ok ? __builtin_nontemporal_load(eb + s + es) : 0;
      uint2 h = *(const uint2*)(tab + (size_t)r * 64 + ch * 8);
      if (ok) {
        a[0] += F8(h.x, 0); a[1] += F8(h.x, 1); a[2] += F8(h.x, 2); a[3] += F8(h.x, 3);
        a[4] += F8(h.y, 0); a[5] += F8(h.y, 1); a[6] += F8(h.y, 2); a[7] += F8(h.y, 3);
      }
    }
#pragma unroll
    for (int j = 0; j < 8; ++j) {
      a[j] += __shfl_xor(a[j], 8, 64);
      a[j] += __shfl_xor(a[j], 16, 64);
      a[j] += __shfl_xor(a[j], 32, 64);
    }
    if (es == 0) {
      floatx4 v0 = {a[0], a[1], a[2], a[3]};
      floatx4 v1 = {a[4], a[5], a[6], a[7]};
      __builtin_nontemporal_store(v0, (floatx4*)(part + (size_t)i * 64 + ch * 8));
      __builtin_nontemporal_store(v1, (floatx4*)(part + (size_t)i * 64 + ch * 8 + 4));
    }
  }
}

// ---------------- aggregate phase B (layer 1): sum slice-1 + partial + self,
// scale/bias/relu -> g1 fp16
__global__ __launch_bounds__(256) void agg_finish(const unsigned char* __restrict__ tab,
    const int* __restrict__ ebuf, const int* __restrict__ estart,
    const int* __restrict__ ecnt, const int* __restrict__ ssplit,
    const float* __restrict__ part, const float* __restrict__ dis,
    const float* __restrict__ bias, __fp16* __restrict__ out, int N) {
  int lane = threadIdx.x & 63;
  int es = lane >> 3;
  int ch = lane & 7;
  float bv[8];
#pragma unroll
  for (int j = 0; j < 8; ++j) bv[j] = bias[ch * 8 + j];
  int wid = (int)((blockIdx.x * blockDim.x + threadIdx.x) >> 6);
  int nwaves = (gridDim.x * blockDim.x) >> 6;
  for (int i = wid; i < N; i += nwaves) {
    int sp = ssplit[i];
    int st = estart[i] + sp;
    int c = ecnt[i] - sp;
    float dsc = dis[i] * MSG_ISCALE;
    const int* eb = ebuf + st;
    float a[8];
#pragma unroll
    for (int j = 0; j < 8; ++j) a[j] = 0.f;
    int s = 0;
    for (; s + 16 <= c; s += 16) {
      int r0 = __builtin_nontemporal_load(eb + s + es);
      int r1 = __builtin_nontemporal_load(eb + s + 8 + es);
      uint2 h0 = *(const uint2*)(tab + (size_t)r0 * 64 + ch * 8);
      uint2 h1 = *(const uint2*)(tab + (size_t)r1 * 64 + ch * 8);
      a[0] += F8(h0.x, 0) + F8(h1.x, 0);
      a[1] += F8(h0.x, 1) + F8(h1.x, 1);
      a[2] += F8(h0.x, 2) + F8(h1.x, 2);
      a[3] += F8(h0.x, 3) + F8(h1.x, 3);
      a[4] += F8(h0.y, 0) + F8(h1.y, 0);
      a[5] += F8(h0.y, 1) + F8(h1.y, 1);
      a[6] += F8(h0.y, 2) + F8(h1.y, 2);
      a[7] += F8(h0.y, 3) + F8(h1.y, 3);
    }
    for (; s < c; s += 8) {
      bool ok = (s + es) < c;
      int r = ok ? __builtin_nontemporal_load(eb + s + es) : 0;
      uint2 h = *(const uint2*)(tab + (size_t)r * 64 + ch * 8);
      if (ok) {
        a[0] += F8(h.x, 0); a[1] += F8(h.x, 1); a[2] += F8(h.x, 2); a[3] += F8(h.x, 3);
        a[4] += F8(h.y, 0); a[5] += F8(h.y, 1); a[6] += F8(h.y, 2); a[7] += F8(h.y, 3);
      }
    }
#pragma unroll
    for (int j = 0; j < 8; ++j) {
      a[j] += __shfl_xor(a[j], 8, 64);
      a[j] += __shfl_xor(a[j], 16, 64);
      a[j] += __shfl_xor(a[j], 32, 64);
    }
    if (es == 0) {
      floatx4 p0 = __builtin_nontemporal_load((const floatx4*)(part + (size_t)i * 64 + ch * 8));
      floatx4 p1 = __builtin_nontemporal_load((const floatx4*)(part + (size_t)i * 64 + ch * 8 + 4));
      uint2 hs = *(const uint2*)(tab + (size_t)i * 64 + ch * 8);
      float sv[8];
      sv[0] = F8(hs.x, 0); sv[1] = F8(hs.x, 1); sv[2] = F8(hs.x, 2); sv[3] = F8(hs.x, 3);
      sv[4] = F8(hs.y, 0); sv[5] = F8(hs.y, 1); sv[6] = F8(hs.y, 2); sv[7] = F8(hs.y, 3);
      float pp[8] = {p0[0], p0[1], p0[2], p0[3], p1[0], p1[1], p1[2], p1[3]};
      half8 r;
#pragma unroll
      for (int j = 0; j < 8; ++j)
        r[j] = (__fp16)fmaxf((a[j] + pp[j] + sv[j]) * dsc + bv[j], 0.f);
      *(half8*)(out + (size_t)i * 64 + ch * 8) = r;
    }
  }
}

// ---------------- aggregate phase B (layer 2): finish + fused batch mean-pool
__global__ __launch_bounds__(256) void agg_finish_pool(const unsigned char* __restrict__ tab,
    const int* __restrict__ ebuf, const int* __restrict__ estart,
    const int* __restrict__ ecnt, const int* __restrict__ ssplit,
    const float* __restrict__ part, const float* __restrict__ dis,
    const float* __restrict__ bias, float* __restrict__ pool, int N) {
  __shared__ float red[4][64];
  int lane = threadIdx.x & 63;
  int es = lane >> 3;
  int ch = lane & 7;
  int wib = threadIdx.x >> 6;
  int i0 = blockIdx.x * 16 + wib * 4;   // 16 nodes/block (one batch), 4 per wave
  float bv[8];
#pragma unroll
  for (int j = 0; j < 8; ++j) bv[j] = bias[ch * 8 + j];
  float ps[8];
#pragma unroll
  for (int j = 0; j < 8; ++j) ps[j] = 0.f;
#pragma unroll
  for (int jj = 0; jj < 4; ++jj) {
    int i = i0 + jj;
    int sp = ssplit[i];
    int st = estart[i] + sp;
    int c = ecnt[i] - sp;
    float dsc = dis[i] * MSG_ISCALE;
    const int* eb = ebuf + st;
    float a[8];
#pragma unroll
    for (int j = 0; j < 8; ++j) a[j] = 0.f;
    int s = 0;
    for (; s + 16 <= c; s += 16) {
      int r0 = __builtin_nontemporal_load(eb + s + es);
      int r1 = __builtin_nontemporal_load(eb + s + 8 + es);
      uint2 h0 = *(const uint2*)(tab + (size_t)r0 * 64 + ch * 8);
      uint2 h1 = *(const uint2*)(tab + (size_t)r1 * 64 + ch * 8);
      a[0] += F8(h0.x, 0) + F8(h1.x, 0);
      a[1] += F8(h0.x, 1) + F8(h1.x, 1);
      a[2] += F8(h0.x, 2) + F8(h1.x, 2);
      a[3] += F8(h0.x, 3) + F8(h1.x, 3);
      a[4] += F8(h0.y, 0) + F8(h1.y, 0);
      a[5] += F8(h0.y, 1) + F8(h1.y, 1);
      a[6] += F8(h0.y, 2) + F8(h1.y, 2);
      a[7] += F8(h0.y, 3) + F8(h1.y, 3);
    }
    for (; s < c; s += 8) {
      bool ok = (s + es) < c;
      int r = ok ? __builtin_nontemporal_load(eb + s + es) : 0;
      uint2 h = *(const uint2*)(tab + (size_t)r * 64 + ch * 8);
      if (ok) {
        a[0] += F8(h.x, 0); a[1] += F8(h.x, 1); a[2] += F8(h.x, 2); a[3] += F8(h.x, 3);
        a[4] += F8(h.y, 0); a[5] += F8(h.y, 1); a[6] += F8(h.y, 2); a[7] += F8(h.y, 3);
      }
    }
#pragma unroll
    for (int j = 0; j < 8; ++j) {
      a[j] += __shfl_xor(a[j], 8, 64);
      a[j] += __shfl_xor(a[j], 16, 64);
      a[j] += __shfl_xor(a[j], 32, 64);
    }
    if (es == 0) {
      floatx4 p0 = __builtin_nontemporal_load((const floatx4*)(part + (size_t)i * 64 + ch * 8));
      floatx4 p1 = __builtin_nontemporal_load((const floatx4*)(part + (size_t)i * 64 + ch * 8 + 4));
      uint2 hs = *(const uint2*)(tab + (size_t)i * 64 + ch * 8);
      float sv[8];
      sv[0] = F8(hs.x, 0); sv[1] = F8(hs.x, 1); sv[2] = F8(hs.x, 2); sv[3] = F8(hs.x, 3);
      sv[4] = F8(hs.y, 0); sv[5] = F8(hs.y, 1); sv[6] = F8(hs.y, 2); sv[7] = F8(hs.y, 3);
      float pp[8] = {p0[0], p0[1], p0[2], p0[3], p1[0], p1[1], p1[2], p1[3]};
#pragma unroll
      for (int j = 0; j < 8; ++j)
        ps[j] += fmaxf((a[j] + pp[j] + sv[j]) * dsc + bv[j], 0.f);
    }
  }
  if (es == 0) {
#pragma unroll
    for (int j = 0; j < 8; ++j) red[wib][ch * 8 + j] = ps[j];
  }
  __syncthreads();
  if (threadIdx.x < 64) {
    int f = threadIdx.x;
    float sum = red[0][f] + red[1][f] + red[2][f] + red[3][f];
    int b = (blockIdx.x * 16) >> 11;
    atomicAdd(&pool[b * 64 + f], sum);
  }
}

// ---------------- classifier: out[b] = (pool[b]/2048) @ cls_w + cls_b
__global__ __launch_bounds__(64) void classify(const float* __restrict__ pool,
    const float* __restrict__ cw, const float* __restrict__ cb,
    float* __restrict__ out) {
  __shared__ float pl[64];
  int b = blockIdx.x;
  int t = threadIdx.x;
  pl[t] = pool[b * 64 + t] * (1.0f / (float)T2);
  __syncthreads();
  if (t < NOUT) {
    float a = cb[t];
#pragma unroll
    for (int k = 0; k < 64; ++k) a += pl[k] * cw[k * NOUT + t];
    out[b * NOUT + t] = a;
  }
}

extern "C" void kernel_launch(void* const* d_in, const int* in_sizes, int n_in,
                              void* d_out, int out_size, void* d_ws, size_t ws_size,
                              hipStream_t stream) {
  const float* x    = (const float*)d_in[0];
  const int*   ei   = (const int*)d_in[1];
  const float* c1w  = (const float*)d_in[2];
  const float* c1b  = (const float*)d_in[3];
  const float* c2w  = (const float*)d_in[4];
  const float* c2b  = (const float*)d_in[5];
  const float* g1w  = (const float*)d_in[6];
  const float* g1b  = (const float*)d_in[7];
  const float* g2w  = (const float*)d_in[8];
  const float* g2b  = (const float*)d_in[9];
  const float* cw   = (const float*)d_in[10];
  const float* cb   = (const float*)d_in[11];
  float* out = (float*)d_out;
  int E = in_sizes[1] / 2;
  const int N = N_NODES;

  // workspace layout (bytes)
  char* ws = (char*)d_ws;
  int2*          gpairs = (int2*)(ws);                     // 18,874,368
  int*           ebuf   = (int*)(ws + 18874368);           //  9,437,184
  int*           rcnt   = (int*)(ws + 28311552);           //      4,096
  int*           estart = (int*)(ws + 28315648);           //    524,288
  int*           ecnt   = (int*)(ws + 28839936);           //    524,288
  int*           ssplit = (int*)(ws + 29364224);           //    524,288
  float*         dis    = (float*)(ws + 29888512);         //    524,288
  float*         pool   = (float*)(ws + 30412800);         //     16,384
  unsigned char* xw     = (unsigned char*)(ws + 30429184); //  8,388,608 (fp8)
  __fp16*        g1     = (__fp16*)(ws + 38817792);        // 16,777,216 (fp16)
  float*         part   = (float*)(ws + 55595008);         // 33,554,432 (fp32)
  char*          Fb     = ws + 89149440;                   // h1 fp32 16MB, then xw2
  float*         h1   = (float*)Fb;                        // 16,777,216
  __fp16*        feat = (__fp16*)(ws + 89149440 + 16777216); // 8,388,608 (fp16)
  unsigned char* xw2  = (unsigned char*)Fb;                //  8,388,608 (fp8, after h1)

  hipMemsetAsync(rcnt, 0, NCB * sizeof(int), stream);
  hipMemsetAsync(pool, 0, BATCH * HID * sizeof(float), stream);

  conv1_kernel<<<dim3(BATCH * 16), dim3(256), 0, stream>>>(x, c1w, c1b, h1);
  conv2_kernel<<<dim3(BATCH * 8), dim3(256), 0, stream>>>(h1, c2w, c2b, feat);
  partition_pairs<<<dim3((E + PC_EDGES - 1) / PC_EDGES), dim3(256), 0, stream>>>(ei, E, rcnt, gpairs);
  build_csr<<<dim3(NCB), dim3(512), 0, stream>>>(gpairs, rcnt, ebuf, estart, ecnt, ssplit, dis);

  gemm1_mfma<<<dim3(512), dim3(256), 0, stream>>>(feat, g1w, dis, xw, N / 16);
  agg_partial<<<dim3(8192), dim3(256), 0, stream>>>(xw, ebuf, estart, ssplit, part, N);
  agg_finish<<<dim3(8192), dim3(256), 0, stream>>>(xw, ebuf, estart, ecnt, ssplit, part, dis, g1b, g1, N);

  gemm2_mfma<<<dim3(512), dim3(256), 0, stream>>>(g1, g2w, dis, xw2, N / 16);
  agg_partial<<<dim3(8192), dim3(256), 0, stream>>>(xw2, ebuf, estart, ssplit, part, N);
  agg_finish_pool<<<dim3(N / 16), dim3(256), 0, stream>>>(xw2, ebuf, estart, ecnt, ssplit, part, dis, g2b, pool, N);

  classify<<<dim3(BATCH), dim3(64), 0, stream>>>(pool, cw, cb, out);
}

// Round 10
// 374.683 us; speedup vs baseline: 1.2165x; 1.2165x over previous
//
#include <hip/hip_runtime.h>
#include <hip/hip_bf16.h>
#include <hip/hip_fp16.h>

// Problem constants
#define BATCH 64
#define C_IN 16
#define T0 8192
#define T1 4096   // after pool1
#define T2 2048   // after pool2 (nodes per batch)
#define N_NODES (BATCH * T2)   // 131072
#define HID 64
#define NOUT 10

// Coarse-bucket edge partition parameters
#define NCB 256
#define CB_SHIFT 9
#define CB_TGT 512
#define RCAP 9216
#define PC_EDGES 2048
#define PC_CAP 28

// packed edge record: bits[0:17) = source r, bits[17:26) = local col (c & 511)
#define PK_RMASK 0x1FFFF

// fp8 message-table scale (values ~0.01 are subnormal in e4m3; x64 normalizes)
#define MSG_SCALE 64.0f
#define MSG_ISCALE (1.0f / 64.0f)

typedef __fp16 half8 __attribute__((ext_vector_type(8)));
typedef float floatx4 __attribute__((ext_vector_type(4)));

#define F8(w, s) __builtin_amdgcn_cvt_f32_fp8((int)(w), (s))

// ---------------- conv1: [64,16,8192] -> relu -> pool2 -> h1 fp16 [64,16,4096]
__global__ __launch_bounds__(256) void conv1_kernel(const float* __restrict__ x,
    const float* __restrict__ w, const float* __restrict__ bias,
    __fp16* __restrict__ h1) {
  __shared__ float xs[16 * 520];
  int b = blockIdx.x >> 4;
  int tp0 = (blockIdx.x & 15) * 256;
  int t_base = tp0 * 2 - 2;
  const float* xb = x + (size_t)b * C_IN * T0;
  for (int idx = threadIdx.x; idx < 16 * 516; idx += 256) {
    int ci = idx / 516;
    int off = idx - ci * 516;
    int gt = t_base + off;
    float v = 0.f;
    if (gt >= 0 && gt < T0) v = xb[ci * T0 + gt];
    xs[ci * 520 + off] = v;
  }
  __syncthreads();
  int tp = threadIdx.x;
  float acc0[16], acc1[16];
#pragma unroll
  for (int co = 0; co < 16; ++co) { acc0[co] = 0.f; acc1[co] = 0.f; }
#pragma unroll 4
  for (int ci = 0; ci < 16; ++ci) {
    float xv[6];
#pragma unroll
    for (int k = 0; k < 6; ++k) xv[k] = xs[ci * 520 + 2 * tp + k];
#pragma unroll
    for (int co = 0; co < 16; ++co) {
#pragma unroll
      for (int k = 0; k < 5; ++k) {
        float wv = w[(co * 16 + ci) * 5 + k];
        acc0[co] += xv[k] * wv;
        acc1[co] += xv[k + 1] * wv;
      }
    }
  }
#pragma unroll
  for (int co = 0; co < 16; ++co) {
    float v = fmaxf(acc0[co], acc1[co]) + bias[co];
    v = fmaxf(v, 0.f);
    h1[((size_t)b * 16 + co) * T1 + tp0 + tp] = (__fp16)v;
  }
}

// ---------------- conv2: h1 fp16 [64,16,4096] -> relu -> pool2 -> feat fp16 [131072,32]
__global__ __launch_bounds__(256) void conv2_kernel(const __fp16* __restrict__ h1,
    const float* __restrict__ w, const float* __restrict__ bias,
    __fp16* __restrict__ feat) {
  __shared__ float xs[16 * 520];
  int b = blockIdx.x >> 3;
  int tp0 = (blockIdx.x & 7) * 256;
  int t_base = tp0 * 2 - 2;
  const __fp16* xb = h1 + (size_t)b * 16 * T1;
  for (int idx = threadIdx.x; idx < 16 * 516; idx += 256) {
    int ci = idx / 516;
    int off = idx - ci * 516;
    int gt = t_base + off;
    float v = 0.f;
    if (gt >= 0 && gt < T1) v = (float)xb[ci * T1 + gt];
    xs[ci * 520 + off] = v;
  }
  __syncthreads();
  int tp = threadIdx.x;
  float acc0[32], acc1[32];
#pragma unroll
  for (int co = 0; co < 32; ++co) { acc0[co] = 0.f; acc1[co] = 0.f; }
#pragma unroll 2
  for (int ci = 0; ci < 16; ++ci) {
    float xv[6];
#pragma unroll
    for (int k = 0; k < 6; ++k) xv[k] = xs[ci * 520 + 2 * tp + k];
#pragma unroll
    for (int co = 0; co < 32; ++co) {
#pragma unroll
      for (int k = 0; k < 5; ++k) {
        float wv = w[(co * 16 + ci) * 5 + k];
        acc0[co] += xv[k] * wv;
        acc1[co] += xv[k + 1] * wv;
      }
    }
  }
  half8 hres[4];
#pragma unroll
  for (int co = 0; co < 32; ++co) {
    float v = fmaxf(acc0[co], acc1[co]) + bias[co];
    hres[co >> 3][co & 7] = (__fp16)fmaxf(v, 0.f);
  }
  size_t nrow = ((size_t)b * T2 + tp0 + tp) * 32;
  half8* f8 = (half8*)(feat + nrow);
#pragma unroll
  for (int j = 0; j < 4; ++j) f8[j] = hres[j];
}

// ---------------- pass C: partition edges (packed 4B records) into bucket regions
__global__ __launch_bounds__(256) void partition_pairs(const int* __restrict__ ei, int E,
    int* __restrict__ rcnt, int* __restrict__ gpairs) {
  __shared__ int lcnt[NCB];
  __shared__ int lpk[NCB * PC_CAP];
  if (threadIdx.x < NCB) lcnt[threadIdx.x] = 0;
  __syncthreads();
  int e0 = blockIdx.x * PC_EDGES;
#pragma unroll
  for (int j = 0; j < PC_EDGES / 256; ++j) {
    int e = e0 + j * 256 + threadIdx.x;
    if (e < E) {
      int r = ei[e];
      int c = ei[E + e];
      int cb = c >> CB_SHIFT;
      int pk = r | ((c & (CB_TGT - 1)) << 17);
      int slot = atomicAdd(&lcnt[cb], 1);
      if (slot < PC_CAP) {
        lpk[cb * PC_CAP + slot] = pk;
      } else {
        int pos = atomicAdd(&rcnt[cb], 1);
        if (pos < RCAP) gpairs[(size_t)cb * RCAP + pos] = pk;
      }
    }
  }
  __syncthreads();
  int t = threadIdx.x;
  if (t < NCB) {
    int n = lcnt[t];
    if (n > PC_CAP) n = PC_CAP;
    if (n > 0) {
      int base = atomicAdd(&rcnt[t], n);
      int* dst = gpairs + (size_t)t * RCAP;
      for (int k = 0; k < n; ++k) {
        int p = base + k;
        if (p < RCAP) dst[p] = lpk[t * PC_CAP + k];
      }
    }
  }
}

// ---------------- pass D: per coarse bucket, exact-degree CSR via wave-scans
__global__ __launch_bounds__(512) void build_csr(const int* __restrict__ gpairs,
    const int* __restrict__ rcnt, int* __restrict__ ebuf,
    int* __restrict__ estart, int* __restrict__ ecnt, float* __restrict__ dis) {
  __shared__ int deg[CB_TGT];
  __shared__ int cur[CB_TGT];
  __shared__ int sc[CB_TGT];
  __shared__ int wsum[8];
  int b = blockIdx.x;
  int t = threadIdx.x;
  deg[t] = 0;
  cur[t] = 0;
  __syncthreads();
  int m = rcnt[b];
  if (m > RCAP) m = RCAP;
  const int* reg = gpairs + (size_t)b * RCAP;
  for (int k = t; k < m; k += 512)
    atomicAdd(&deg[(reg[k] >> 17) & (CB_TGT - 1)], 1);
  __syncthreads();
  int d = deg[t];
  // inclusive scan within each 64-lane wave (8 waves x 64)
  int lane = t & 63;
  int wv = t >> 6;
  int sum = d;
#pragma unroll
  for (int off = 1; off < 64; off <<= 1) {
    int v = __shfl_up(sum, off, 64);
    if (lane >= off) sum += v;
  }
  if (lane == 63) wsum[wv] = sum;
  __syncthreads();
  int prefix = 0;
#pragma unroll
  for (int i = 0; i < 8; ++i) prefix += (i < wv) ? wsum[i] : 0;
  int excl = prefix + sum - d;
  int gi = (b << CB_SHIFT) + t;
  int base = b * RCAP;
  estart[gi] = base + excl;
  ecnt[gi] = d;
  dis[gi] = rsqrtf((float)d + 1.0f);
  sc[t] = excl;
  __syncthreads();
  for (int k = t; k < m; k += 512) {
    int p = reg[k];
    int lc = (p >> 17) & (CB_TGT - 1);
    int off = atomicAdd(&cur[lc], 1);
    ebuf[base + sc[lc] + off] = p & PK_RMASK;
  }
}

// ---------------- MFMA node GEMM, K=32: xw[n] = fp8( 64 * dis[n] * (feat[n] @ W) )
__global__ __launch_bounds__(256) void gemm1_mfma(const __fp16* __restrict__ in,
    const float* __restrict__ W, const float* __restrict__ dis,
    unsigned char* __restrict__ out, int NT) {
  int lane = threadIdx.x & 63;
  int m = lane & 15;
  int q = lane >> 4;
  half8 bf[4];
#pragma unroll
  for (int t = 0; t < 4; ++t)
#pragma unroll
    for (int j = 0; j < 8; ++j)
      bf[t][j] = (__fp16)W[(q * 8 + j) * 64 + t * 16 + m];
  int wid = (int)((blockIdx.x * blockDim.x + threadIdx.x) >> 6);
  int nwaves = (gridDim.x * blockDim.x) >> 6;
  for (int tile = wid; tile < NT; tile += nwaves) {
    int base = tile * 16;
    half8 a = *(const half8*)(in + (size_t)(base + m) * 32 + q * 8);
    float d[4];
#pragma unroll
    for (int r = 0; r < 4; ++r) d[r] = dis[base + q * 4 + r] * MSG_SCALE;
#pragma unroll
    for (int t = 0; t < 4; ++t) {
      floatx4 acc = {0.f, 0.f, 0.f, 0.f};
      acc = __builtin_amdgcn_mfma_f32_16x16x32_f16(a, bf[t], acc, 0, 0, 0);
#pragma unroll
      for (int r = 0; r < 4; ++r) {
        float v = acc[r] * d[r];
        int pk = __builtin_amdgcn_cvt_pk_fp8_f32(v, v, 0, false);
        out[(size_t)(base + q * 4 + r) * 64 + t * 16 + m] = (unsigned char)(pk & 0xFF);
      }
    }
  }
}

// ---------------- MFMA node GEMM, K=64: xw2[n] = fp8( 64 * dis[n] * (g1[n] @ W) )
__global__ __launch_bounds__(256) void gemm2_mfma(const __fp16* __restrict__ in,
    const float* __restrict__ W, const float* __restrict__ dis,
    unsigned char* __restrict__ out, int NT) {
  int lane = threadIdx.x & 63;
  int m = lane & 15;
  int q = lane >> 4;
  half8 bf[4][2];
#pragma unroll
  for (int t = 0; t < 4; ++t)
#pragma unroll
    for (int s = 0; s < 2; ++s)
#pragma unroll
      for (int j = 0; j < 8; ++j)
        bf[t][s][j] = (__fp16)W[(s * 32 + q * 8 + j) * 64 + t * 16 + m];
  int wid = (int)((blockIdx.x * blockDim.x + threadIdx.x) >> 6);
  int nwaves = (gridDim.x * blockDim.x) >> 6;
  for (int tile = wid; tile < NT; tile += nwaves) {
    int base = tile * 16;
    half8 a0 = *(const half8*)(in + (size_t)(base + m) * 64 + q * 8);
    half8 a1 = *(const half8*)(in + (size_t)(base + m) * 64 + 32 + q * 8);
    float d[4];
#pragma unroll
    for (int r = 0; r < 4; ++r) d[r] = dis[base + q * 4 + r] * MSG_SCALE;
#pragma unroll
    for (int t = 0; t < 4; ++t) {
      floatx4 acc = {0.f, 0.f, 0.f, 0.f};
      acc = __builtin_amdgcn_mfma_f32_16x16x32_f16(a0, bf[t][0], acc, 0, 0, 0);
      acc = __builtin_amdgcn_mfma_f32_16x16x32_f16(a1, bf[t][1], acc, 0, 0, 0);
#pragma unroll
      for (int r = 0; r < 4; ++r) {
        float v = acc[r] * d[r];
        int pk = __builtin_amdgcn_cvt_pk_fp8_f32(v, v, 0, false);
        out[(size_t)(base + q * 4 + r) * 64 + t * 16 + m] = (unsigned char)(pk & 0xFF);
      }
    }
  }
}

// ---------------- GCN aggregate layer-1: fp8 table, 64B row = 1 cache line.
// Wave = 8 edge-slots x 8 lanes (8B/lane); one instruction gathers 8 rows.
__global__ __launch_bounds__(256) void gcn_aggregate(const unsigned char* __restrict__ tab,
    const int* __restrict__ ebuf, const int* __restrict__ estart,
    const int* __restrict__ ecnt, const float* __restrict__ dis,
    const float* __restrict__ bias, __fp16* __restrict__ out, int N) {
  int lane = threadIdx.x & 63;
  int es = lane >> 3;        // edge slot 0..7
  int ch = lane & 7;         // feature octet: features ch*8 .. ch*8+7
  float bv[8];
#pragma unroll
  for (int j = 0; j < 8; ++j) bv[j] = bias[ch * 8 + j];
  int wid = (int)((blockIdx.x * blockDim.x + threadIdx.x) >> 6);
  int nwaves = (gridDim.x * blockDim.x) >> 6;
  for (int i = wid; i < N; i += nwaves) {
    int st = estart[i];
    int c = ecnt[i];
    float dsc = dis[i] * MSG_ISCALE;
    const int* eb = ebuf + st;
    float a[8];
#pragma unroll
    for (int j = 0; j < 8; ++j) a[j] = 0.f;
    int s = 0;
    for (; s + 16 <= c; s += 16) {
      int r0 = eb[s + es];
      int r1 = eb[s + 8 + es];
      uint2 h0 = *(const uint2*)(tab + (size_t)r0 * 64 + ch * 8);
      uint2 h1 = *(const uint2*)(tab + (size_t)r1 * 64 + ch * 8);
      a[0] += F8(h0.x, 0) + F8(h1.x, 0);
      a[1] += F8(h0.x, 1) + F8(h1.x, 1);
      a[2] += F8(h0.x, 2) + F8(h1.x, 2);
      a[3] += F8(h0.x, 3) + F8(h1.x, 3);
      a[4] += F8(h0.y, 0) + F8(h1.y, 0);
      a[5] += F8(h0.y, 1) + F8(h1.y, 1);
      a[6] += F8(h0.y, 2) + F8(h1.y, 2);
      a[7] += F8(h0.y, 3) + F8(h1.y, 3);
    }
    for (; s < c; s += 8) {
      bool ok = (s + es) < c;
      int r = ok ? eb[s + es] : 0;
      uint2 h = *(const uint2*)(tab + (size_t)r * 64 + ch * 8);
      if (ok) {
        a[0] += F8(h.x, 0); a[1] += F8(h.x, 1); a[2] += F8(h.x, 2); a[3] += F8(h.x, 3);
        a[4] += F8(h.y, 0); a[5] += F8(h.y, 1); a[6] += F8(h.y, 2); a[7] += F8(h.y, 3);
      }
    }
#pragma unroll
    for (int j = 0; j < 8; ++j) {
      a[j] += __shfl_xor(a[j], 8, 64);
      a[j] += __shfl_xor(a[j], 16, 64);
      a[j] += __shfl_xor(a[j], 32, 64);
    }
    uint2 hs = *(const uint2*)(tab + (size_t)i * 64 + ch * 8);
    float sv[8];
    sv[0] = F8(hs.x, 0); sv[1] = F8(hs.x, 1); sv[2] = F8(hs.x, 2); sv[3] = F8(hs.x, 3);
    sv[4] = F8(hs.y, 0); sv[5] = F8(hs.y, 1); sv[6] = F8(hs.y, 2); sv[7] = F8(hs.y, 3);
    if (es == 0) {
      half8 r;
#pragma unroll
      for (int j = 0; j < 8; ++j)
        r[j] = (__fp16)fmaxf((a[j] + sv[j]) * dsc + bv[j], 0.f);
      *(half8*)(out + (size_t)i * 64 + ch * 8) = r;
    }
  }
}

// ---------------- GCN aggregate layer-2 (fp8 table) fused with batch mean-pool
__global__ __launch_bounds__(256) void gcn_aggregate_pool(const unsigned char* __restrict__ tab,
    const int* __restrict__ ebuf, const int* __restrict__ estart,
    const int* __restrict__ ecnt, const float* __restrict__ dis,
    const float* __restrict__ bias, float* __restrict__ pool, int N) {
  __shared__ float red[4][64];
  int lane = threadIdx.x & 63;
  int es = lane >> 3;
  int ch = lane & 7;
  int wib = threadIdx.x >> 6;
  int i0 = blockIdx.x * 16 + wib * 4;   // 16 nodes/block (one batch), 4 per wave
  float bv[8];
#pragma unroll
  for (int j = 0; j < 8; ++j) bv[j] = bias[ch * 8 + j];
  float ps[8];
#pragma unroll
  for (int j = 0; j < 8; ++j) ps[j] = 0.f;
#pragma unroll
  for (int jj = 0; jj < 4; ++jj) {
    int i = i0 + jj;
    int st = estart[i];
    int c = ecnt[i];
    float dsc = dis[i] * MSG_ISCALE;
    const int* eb = ebuf + st;
    float a[8];
#pragma unroll
    for (int j = 0; j < 8; ++j) a[j] = 0.f;
    int s = 0;
    for (; s + 16 <= c; s += 16) {
      int r0 = eb[s + es];
      int r1 = eb[s + 8 + es];
      uint2 h0 = *(const uint2*)(tab + (size_t)r0 * 64 + ch * 8);
      uint2 h1 = *(const uint2*)(tab + (size_t)r1 * 64 + ch * 8);
      a[0] += F8(h0.x, 0) + F8(h1.x, 0);
      a[1] += F8(h0.x, 1) + F8(h1.x, 1);
      a[2] += F8(h0.x, 2) + F8(h1.x, 2);
      a[3] += F8(h0.x, 3) + F8(h1.x, 3);
      a[4] += F8(h0.y, 0) + F8(h1.y, 0);
      a[5] += F8(h0.y, 1) + F8(h1.y, 1);
      a[6] += F8(h0.y, 2) + F8(h1.y, 2);
      a[7] += F8(h0.y, 3) + F8(h1.y, 3);
    }
    for (; s < c; s += 8) {
      bool ok = (s + es) < c;
      int r = ok ? eb[s + es] : 0;
      uint2 h = *(const uint2*)(tab + (size_t)r * 64 + ch * 8);
      if (ok) {
        a[0] += F8(h.x, 0); a[1] += F8(h.x, 1); a[2] += F8(h.x, 2); a[3] += F8(h.x, 3);
        a[4] += F8(h.y, 0); a[5] += F8(h.y, 1); a[6] += F8(h.y, 2); a[7] += F8(h.y, 3);
      }
    }
#pragma unroll
    for (int j = 0; j < 8; ++j) {
      a[j] += __shfl_xor(a[j], 8, 64);
      a[j] += __shfl_xor(a[j], 16, 64);
      a[j] += __shfl_xor(a[j], 32, 64);
    }
    uint2 hs = *(const uint2*)(tab + (size_t)i * 64 + ch * 8);
    float sv[8];
    sv[0] = F8(hs.x, 0); sv[1] = F8(hs.x, 1); sv[2] = F8(hs.x, 2); sv[3] = F8(hs.x, 3);
    sv[4] = F8(hs.y, 0); sv[5] = F8(hs.y, 1); sv[6] = F8(hs.y, 2); sv[7] = F8(hs.y, 3);
#pragma unroll
    for (int j = 0; j < 8; ++j)
      ps[j] += fmaxf((a[j] + sv[j]) * dsc + bv[j], 0.f);
  }
  if (es == 0) {
#pragma unroll
    for (int j = 0; j < 8; ++j) red[wib][ch * 8 + j] = ps[j];
  }
  __syncthreads();
  if (threadIdx.x < 64) {
    int f = threadIdx.x;
    float sum = red[0][f] + red[1][f] + red[2][f] + red[3][f];
    int b = (blockIdx.x * 16) >> 11;
    atomicAdd(&pool[b * 64 + f], sum);
  }
}

// ---------------- classifier: out[b] = (pool[b]/2048) @ cls_w + cls_b
__global__ __launch_bounds__(64) void classify(const float* __restrict__ pool,
    const float* __restrict__ cw, const float* __restrict__ cb,
    float* __restrict__ out) {
  __shared__ float pl[64];
  int b = blockIdx.x;
  int t = threadIdx.x;
  pl[t] = pool[b * 64 + t] * (1.0f / (float)T2);
  __syncthreads();
  if (t < NOUT) {
    float a = cb[t];
#pragma unroll
    for (int k = 0; k < 64; ++k) a += pl[k] * cw[k * NOUT + t];
    out[b * NOUT + t] = a;
  }
}

extern "C" void kernel_launch(void* const* d_in, const int* in_sizes, int n_in,
                              void* d_out, int out_size, void* d_ws, size_t ws_size,
                              hipStream_t stream) {
  const float* x    = (const float*)d_in[0];
  const int*   ei   = (const int*)d_in[1];
  const float* c1w  = (const float*)d_in[2];
  const float* c1b  = (const float*)d_in[3];
  const float* c2w  = (const float*)d_in[4];
  const float* c2b  = (const float*)d_in[5];
  const float* g1w  = (const float*)d_in[6];
  const float* g1b  = (const float*)d_in[7];
  const float* g2w  = (const float*)d_in[8];
  const float* g2b  = (const float*)d_in[9];
  const float* cw   = (const float*)d_in[10];
  const float* cb   = (const float*)d_in[11];
  float* out = (float*)d_out;
  int E = in_sizes[1] / 2;
  const int N = N_NODES;

  // workspace layout (bytes)
  char* ws = (char*)d_ws;
  int*           gpairs = (int*)(ws);                      //  9,437,184 (packed 4B)
  int*           ebuf   = (int*)(ws + 9437184);            //  9,437,184
  int*           rcnt   = (int*)(ws + 18874368);           //      4,096
  int*           estart = (int*)(ws + 18878464);           //    524,288
  int*           ecnt   = (int*)(ws + 19402752);           //    524,288
  float*         dis    = (float*)(ws + 19927040);         //    524,288
  float*         pool   = (float*)(ws + 20451328);         //     16,384
  unsigned char* xw     = (unsigned char*)(ws + 20467712); //  8,388,608 (fp8)
  __fp16*        g1     = (__fp16*)(ws + 28856320);        // 16,777,216 (fp16)
  __fp16*        h1     = (__fp16*)(ws + 45633536);        //  8,388,608 (fp16)
  __fp16*        feat   = (__fp16*)(ws + 54022144);        //  8,388,608 (fp16)
  unsigned char* xw2    = (unsigned char*)(ws + 45633536); //  8,388,608 (fp8, reuses h1)

  hipMemsetAsync(rcnt, 0, NCB * sizeof(int), stream);
  hipMemsetAsync(pool, 0, BATCH * HID * sizeof(float), stream);

  conv1_kernel<<<dim3(BATCH * 16), dim3(256), 0, stream>>>(x, c1w, c1b, h1);
  conv2_kernel<<<dim3(BATCH * 8), dim3(256), 0, stream>>>(h1, c2w, c2b, feat);
  partition_pairs<<<dim3((E + PC_EDGES - 1) / PC_EDGES), dim3(256), 0, stream>>>(ei, E, rcnt, gpairs);
  build_csr<<<dim3(NCB), dim3(512), 0, stream>>>(gpairs, rcnt, ebuf, estart, ecnt, dis);

  gemm1_mfma<<<dim3(512), dim3(256), 0, stream>>>(feat, g1w, dis, xw, N / 16);
  gcn_aggregate<<<dim3(8192), dim3(256), 0, stream>>>(xw, ebuf, estart, ecnt, dis, g1b, g1, N);

  gemm2_mfma<<<dim3(512), dim3(256), 0, stream>>>(g1, g2w, dis, xw2, N / 16);
  gcn_aggregate_pool<<<dim3(N / 16), dim3(256), 0, stream>>>(xw2, ebuf, estart, ecnt, dis, g2b, pool, N);

  classify<<<dim3(BATCH), dim3(64), 0, stream>>>(pool, cw, cb, out);
}

// Round 11
// 364.671 us; speedup vs baseline: 1.2499x; 1.0275x over previous
//
#include <hip/hip_runtime.h>
#include <hip/hip_bf16.h>
#include <hip/hip_fp16.h>

// Problem constants
#define BATCH 64
#define C_IN 16
#define T0 8192
#define T1 4096   // after pool1
#define T2 2048   // after pool2 (nodes per batch)
#define N_NODES (BATCH * T2)   // 131072
#define HID 64
#define NOUT 10

// Coarse-bucket edge partition parameters
#define NCB 256
#define CB_SHIFT 9
#define CB_TGT 512
#define RCAP 9216
#define PC_EDGES 2048
#define PC_CAP 28

// packed edge record: bits[0:17) = source r, bits[17:26) = local col
#define PK_RMASK 0x1FFFF

// fp8 message-table scale
#define MSG_SCALE 64.0f
#define MSG_ISCALE (1.0f / 64.0f)

typedef __fp16 half8 __attribute__((ext_vector_type(8)));
typedef float floatx4 __attribute__((ext_vector_type(4)));

#define F8(w, s) __builtin_amdgcn_cvt_f32_fp8((int)(w), (s))

// ---------------- conv1: [64,16,8192] -> relu -> pool2 -> h1 fp16 [64,16,4096]
__global__ __launch_bounds__(256) void conv1_kernel(const float* __restrict__ x,
    const float* __restrict__ w, const float* __restrict__ bias,
    __fp16* __restrict__ h1) {
  __shared__ float xs[16 * 520];
  int b = blockIdx.x >> 4;
  int tp0 = (blockIdx.x & 15) * 256;
  int t_base = tp0 * 2 - 2;
  const float* xb = x + (size_t)b * C_IN * T0;
  for (int idx = threadIdx.x; idx < 16 * 516; idx += 256) {
    int ci = idx / 516;
    int off = idx - ci * 516;
    int gt = t_base + off;
    float v = 0.f;
    if (gt >= 0 && gt < T0) v = xb[ci * T0 + gt];
    xs[ci * 520 + off] = v;
  }
  __syncthreads();
  int tp = threadIdx.x;
  float acc0[16], acc1[16];
#pragma unroll
  for (int co = 0; co < 16; ++co) { acc0[co] = 0.f; acc1[co] = 0.f; }
#pragma unroll 4
  for (int ci = 0; ci < 16; ++ci) {
    float xv[6];
#pragma unroll
    for (int k = 0; k < 6; ++k) xv[k] = xs[ci * 520 + 2 * tp + k];
#pragma unroll
    for (int co = 0; co < 16; ++co) {
#pragma unroll
      for (int k = 0; k < 5; ++k) {
        float wv = w[(co * 16 + ci) * 5 + k];
        acc0[co] += xv[k] * wv;
        acc1[co] += xv[k + 1] * wv;
      }
    }
  }
#pragma unroll
  for (int co = 0; co < 16; ++co) {
    float v = fmaxf(acc0[co], acc1[co]) + bias[co];
    v = fmaxf(v, 0.f);
    h1[((size_t)b * 16 + co) * T1 + tp0 + tp] = (__fp16)v;
  }
}

// ---------------- conv2 + gemm1 fused: h1 -> relu/pool -> (LDS) -> MFMA @W1
// -> xw fp8 (feat never materialized)
__global__ __launch_bounds__(256) void conv2_gemm1(const __fp16* __restrict__ h1,
    const float* __restrict__ w, const float* __restrict__ bias,
    const float* __restrict__ W1, const float* __restrict__ dis,
    unsigned char* __restrict__ xw) {
  __shared__ float xs[16 * 520];
  __shared__ __fp16 fs[256 * 40];   // 256 node rows, stride 40 halves (80B)
  int b = blockIdx.x >> 3;
  int tp0 = (blockIdx.x & 7) * 256;
  int t_base = tp0 * 2 - 2;
  const __fp16* xb = h1 + (size_t)b * 16 * T1;
  for (int idx = threadIdx.x; idx < 16 * 516; idx += 256) {
    int ci = idx / 516;
    int off = idx - ci * 516;
    int gt = t_base + off;
    float v = 0.f;
    if (gt >= 0 && gt < T1) v = (float)xb[ci * T1 + gt];
    xs[ci * 520 + off] = v;
  }
  __syncthreads();
  int tp = threadIdx.x;
  float acc0[32], acc1[32];
#pragma unroll
  for (int co = 0; co < 32; ++co) { acc0[co] = 0.f; acc1[co] = 0.f; }
#pragma unroll 2
  for (int ci = 0; ci < 16; ++ci) {
    float xv[6];
#pragma unroll
    for (int k = 0; k < 6; ++k) xv[k] = xs[ci * 520 + 2 * tp + k];
#pragma unroll
    for (int co = 0; co < 32; ++co) {
#pragma unroll
      for (int k = 0; k < 5; ++k) {
        float wv = w[(co * 16 + ci) * 5 + k];
        acc0[co] += xv[k] * wv;
        acc1[co] += xv[k + 1] * wv;
      }
    }
  }
  half8 hres[4];
#pragma unroll
  for (int co = 0; co < 32; ++co) {
    float v = fmaxf(acc0[co], acc1[co]) + bias[co];
    hres[co >> 3][co & 7] = (__fp16)fmaxf(v, 0.f);
  }
  half8* frow = (half8*)(fs + tp * 40);
#pragma unroll
  for (int j = 0; j < 4; ++j) frow[j] = hres[j];
  __syncthreads();
  // gemm1: each wave handles 4 tiles of 16 nodes, K=32 MFMA
  int lane = threadIdx.x & 63;
  int m = lane & 15;
  int q = lane >> 4;
  int wib = threadIdx.x >> 6;
  half8 bf[4];
#pragma unroll
  for (int t = 0; t < 4; ++t)
#pragma unroll
    for (int j = 0; j < 8; ++j)
      bf[t][j] = (__fp16)W1[(q * 8 + j) * 64 + t * 16 + m];
  int gnode0 = b * T2 + tp0;
#pragma unroll
  for (int tt = 0; tt < 4; ++tt) {
    int lbase = (wib * 4 + tt) * 16;
    half8 a = *(const half8*)(fs + (lbase + m) * 40 + q * 8);
    float d[4];
#pragma unroll
    for (int r = 0; r < 4; ++r) d[r] = dis[gnode0 + lbase + q * 4 + r] * MSG_SCALE;
#pragma unroll
    for (int t = 0; t < 4; ++t) {
      floatx4 acc = {0.f, 0.f, 0.f, 0.f};
      acc = __builtin_amdgcn_mfma_f32_16x16x32_f16(a, bf[t], acc, 0, 0, 0);
#pragma unroll
      for (int r = 0; r < 4; ++r) {
        float v = acc[r] * d[r];
        int pk = __builtin_amdgcn_cvt_pk_fp8_f32(v, v, 0, false);
        xw[(size_t)(gnode0 + lbase + q * 4 + r) * 64 + t * 16 + m] = (unsigned char)(pk & 0xFF);
      }
    }
  }
}

// ---------------- pass C: partition edges (packed 4B records) into bucket regions
__global__ __launch_bounds__(256) void partition_pairs(const int* __restrict__ ei, int E,
    int* __restrict__ rcnt, int* __restrict__ gpairs) {
  __shared__ int lcnt[NCB];
  __shared__ int lpk[NCB * PC_CAP];
  if (threadIdx.x < NCB) lcnt[threadIdx.x] = 0;
  __syncthreads();
  int e0 = blockIdx.x * PC_EDGES;
#pragma unroll
  for (int j = 0; j < PC_EDGES / 256; ++j) {
    int e = e0 + j * 256 + threadIdx.x;
    if (e < E) {
      int r = ei[e];
      int c = ei[E + e];
      int cb = c >> CB_SHIFT;
      int pk = r | ((c & (CB_TGT - 1)) << 17);
      int slot = atomicAdd(&lcnt[cb], 1);
      if (slot < PC_CAP) {
        lpk[cb * PC_CAP + slot] = pk;
      } else {
        int pos = atomicAdd(&rcnt[cb], 1);
        if (pos < RCAP) gpairs[(size_t)cb * RCAP + pos] = pk;
      }
    }
  }
  __syncthreads();
  int t = threadIdx.x;
  if (t < NCB) {
    int n = lcnt[t];
    if (n > PC_CAP) n = PC_CAP;
    if (n > 0) {
      int base = atomicAdd(&rcnt[t], n);
      int* dst = gpairs + (size_t)t * RCAP;
      for (int k = 0; k < n; ++k) {
        int p = base + k;
        if (p < RCAP) dst[p] = lpk[t * PC_CAP + k];
      }
    }
  }
}

// ---------------- pass D: per coarse bucket, exact-degree CSR via wave-scans
__global__ __launch_bounds__(512) void build_csr(const int* __restrict__ gpairs,
    const int* __restrict__ rcnt, int* __restrict__ ebuf,
    int* __restrict__ estart, int* __restrict__ ecnt, float* __restrict__ dis) {
  __shared__ int deg[CB_TGT];
  __shared__ int cur[CB_TGT];
  __shared__ int sc[CB_TGT];
  __shared__ int wsum[8];
  int b = blockIdx.x;
  int t = threadIdx.x;
  deg[t] = 0;
  cur[t] = 0;
  __syncthreads();
  int m = rcnt[b];
  if (m > RCAP) m = RCAP;
  const int* reg = gpairs + (size_t)b * RCAP;
  for (int k = t; k < m; k += 512)
    atomicAdd(&deg[(reg[k] >> 17) & (CB_TGT - 1)], 1);
  __syncthreads();
  int d = deg[t];
  int lane = t & 63;
  int wv = t >> 6;
  int sum = d;
#pragma unroll
  for (int off = 1; off < 64; off <<= 1) {
    int v = __shfl_up(sum, off, 64);
    if (lane >= off) sum += v;
  }
  if (lane == 63) wsum[wv] = sum;
  __syncthreads();
  int prefix = 0;
#pragma unroll
  for (int i = 0; i < 8; ++i) prefix += (i < wv) ? wsum[i] : 0;
  int excl = prefix + sum - d;
  int gi = (b << CB_SHIFT) + t;
  int base = b * RCAP;
  estart[gi] = base + excl;
  ecnt[gi] = d;
  dis[gi] = rsqrtf((float)d + 1.0f);
  sc[t] = excl;
  __syncthreads();
  for (int k = t; k < m; k += 512) {
    int p = reg[k];
    int lc = (p >> 17) & (CB_TGT - 1);
    int off = atomicAdd(&cur[lc], 1);
    ebuf[base + sc[lc] + off] = p & PK_RMASK;
  }
}

// ---------------- agg1 + gemm2 fused: block = 16 consecutive nodes.
// Gather layer-1 (fp8 table), g1 rows staged in LDS fp16, then each wave does
// the K=64 MFMA for its 16 output cols -> xw2 fp8 (g1 never materialized).
__global__ __launch_bounds__(256) void agg1_gemm2(const unsigned char* __restrict__ tab,
    const int* __restrict__ ebuf, const int* __restrict__ estart,
    const int* __restrict__ ecnt, const float* __restrict__ dis,
    const float* __restrict__ bias, const float* __restrict__ W2,
    unsigned char* __restrict__ xw2, int N) {
  __shared__ __fp16 g1s[16 * 72];   // 16 node rows, stride 72 halves (144B)
  int lane = threadIdx.x & 63;
  int es = lane >> 3;
  int ch = lane & 7;
  int wib = threadIdx.x >> 6;
  int base16 = blockIdx.x * 16;
  float bv[8];
#pragma unroll
  for (int j = 0; j < 8; ++j) bv[j] = bias[ch * 8 + j];
#pragma unroll
  for (int jj = 0; jj < 4; ++jj) {
    int i = base16 + wib * 4 + jj;
    int st = estart[i];
    int c = ecnt[i];
    float dsc = dis[i] * MSG_ISCALE;
    const int* eb = ebuf + st;
    float a[8];
#pragma unroll
    for (int j = 0; j < 8; ++j) a[j] = 0.f;
    int s = 0;
    for (; s + 16 <= c; s += 16) {
      int r0 = eb[s + es];
      int r1 = eb[s + 8 + es];
      uint2 h0 = *(const uint2*)(tab + (size_t)r0 * 64 + ch * 8);
      uint2 h1 = *(const uint2*)(tab + (size_t)r1 * 64 + ch * 8);
      a[0] += F8(h0.x, 0) + F8(h1.x, 0);
      a[1] += F8(h0.x, 1) + F8(h1.x, 1);
      a[2] += F8(h0.x, 2) + F8(h1.x, 2);
      a[3] += F8(h0.x, 3) + F8(h1.x, 3);
      a[4] += F8(h0.y, 0) + F8(h1.y, 0);
      a[5] += F8(h0.y, 1) + F8(h1.y, 1);
      a[6] += F8(h0.y, 2) + F8(h1.y, 2);
      a[7] += F8(h0.y, 3) + F8(h1.y, 3);
    }
    for (; s < c; s += 8) {
      bool ok = (s + es) < c;
      int r = ok ? eb[s + es] : 0;
      uint2 h = *(const uint2*)(tab + (size_t)r * 64 + ch * 8);
      if (ok) {
        a[0] += F8(h.x, 0); a[1] += F8(h.x, 1); a[2] += F8(h.x, 2); a[3] += F8(h.x, 3);
        a[4] += F8(h.y, 0); a[5] += F8(h.y, 1); a[6] += F8(h.y, 2); a[7] += F8(h.y, 3);
      }
    }
#pragma unroll
    for (int j = 0; j < 8; ++j) {
      a[j] += __shfl_xor(a[j], 8, 64);
      a[j] += __shfl_xor(a[j], 16, 64);
      a[j] += __shfl_xor(a[j], 32, 64);
    }
    uint2 hs = *(const uint2*)(tab + (size_t)i * 64 + ch * 8);
    float sv[8];
    sv[0] = F8(hs.x, 0); sv[1] = F8(hs.x, 1); sv[2] = F8(hs.x, 2); sv[3] = F8(hs.x, 3);
    sv[4] = F8(hs.y, 0); sv[5] = F8(hs.y, 1); sv[6] = F8(hs.y, 2); sv[7] = F8(hs.y, 3);
    if (es == 0) {
      half8 r;
#pragma unroll
      for (int j = 0; j < 8; ++j)
        r[j] = (__fp16)fmaxf((a[j] + sv[j]) * dsc + bv[j], 0.f);
      *(half8*)(g1s + (wib * 4 + jj) * 72 + ch * 8) = r;
    }
  }
  __syncthreads();
  // gemm2 epilogue: wave wib computes output columns wib*16..wib*16+15
  int m = lane & 15;
  int q = lane >> 4;
  half8 b0, b1;
#pragma unroll
  for (int j = 0; j < 8; ++j) {
    b0[j] = (__fp16)W2[(q * 8 + j) * 64 + wib * 16 + m];
    b1[j] = (__fp16)W2[(32 + q * 8 + j) * 64 + wib * 16 + m];
  }
  half8 a0 = *(const half8*)(g1s + m * 72 + q * 8);
  half8 a1 = *(const half8*)(g1s + m * 72 + 32 + q * 8);
  floatx4 acc = {0.f, 0.f, 0.f, 0.f};
  acc = __builtin_amdgcn_mfma_f32_16x16x32_f16(a0, b0, acc, 0, 0, 0);
  acc = __builtin_amdgcn_mfma_f32_16x16x32_f16(a1, b1, acc, 0, 0, 0);
#pragma unroll
  for (int r = 0; r < 4; ++r) {
    int node = base16 + q * 4 + r;
    float v = acc[r] * dis[node] * MSG_SCALE;
    int pk = __builtin_amdgcn_cvt_pk_fp8_f32(v, v, 0, false);
    xw2[(size_t)node * 64 + wib * 16 + m] = (unsigned char)(pk & 0xFF);
  }
}

// ---------------- GCN aggregate layer-2 (fp8 table) fused with batch mean-pool
__global__ __launch_bounds__(256) void gcn_aggregate_pool(const unsigned char* __restrict__ tab,
    const int* __restrict__ ebuf, const int* __restrict__ estart,
    const int* __restrict__ ecnt, const float* __restrict__ dis,
    const float* __restrict__ bias, float* __restrict__ pool, int N) {
  __shared__ float red[4][64];
  int lane = threadIdx.x & 63;
  int es = lane >> 3;
  int ch = lane & 7;
  int wib = threadIdx.x >> 6;
  int i0 = blockIdx.x * 16 + wib * 4;
  float bv[8];
#pragma unroll
  for (int j = 0; j < 8; ++j) bv[j] = bias[ch * 8 + j];
  float ps[8];
#pragma unroll
  for (int j = 0; j < 8; ++j) ps[j] = 0.f;
#pragma unroll
  for (int jj = 0; jj < 4; ++jj) {
    int i = i0 + jj;
    int st = estart[i];
    int c = ecnt[i];
    float dsc = dis[i] * MSG_ISCALE;
    const int* eb = ebuf + st;
    float a[8];
#pragma unroll
    for (int j = 0; j < 8; ++j) a[j] = 0.f;
    int s = 0;
    for (; s + 16 <= c; s += 16) {
      int r0 = eb[s + es];
      int r1 = eb[s + 8 + es];
      uint2 h0 = *(const uint2*)(tab + (size_t)r0 * 64 + ch * 8);
      uint2 h1 = *(const uint2*)(tab + (size_t)r1 * 64 + ch * 8);
      a[0] += F8(h0.x, 0) + F8(h1.x, 0);
      a[1] += F8(h0.x, 1) + F8(h1.x, 1);
      a[2] += F8(h0.x, 2) + F8(h1.x, 2);
      a[3] += F8(h0.x, 3) + F8(h1.x, 3);
      a[4] += F8(h0.y, 0) + F8(h1.y, 0);
      a[5] += F8(h0.y, 1) + F8(h1.y, 1);
      a[6] += F8(h0.y, 2) + F8(h1.y, 2);
      a[7] += F8(h0.y, 3) + F8(h1.y, 3);
    }
    for (; s < c; s += 8) {
      bool ok = (s + es) < c;
      int r = ok ? eb[s + es] : 0;
      uint2 h = *(const uint2*)(tab + (size_t)r * 64 + ch * 8);
      if (ok) {
        a[0] += F8(h.x, 0); a[1] += F8(h.x, 1); a[2] += F8(h.x, 2); a[3] += F8(h.x, 3);
        a[4] += F8(h.y, 0); a[5] += F8(h.y, 1); a[6] += F8(h.y, 2); a[7] += F8(h.y, 3);
      }
    }
#pragma unroll
    for (int j = 0; j < 8; ++j) {
      a[j] += __shfl_xor(a[j], 8, 64);
      a[j] += __shfl_xor(a[j], 16, 64);
      a[j] += __shfl_xor(a[j], 32, 64);
    }
    uint2 hs = *(const uint2*)(tab + (size_t)i * 64 + ch * 8);
    float sv[8];
    sv[0] = F8(hs.x, 0); sv[1] = F8(hs.x, 1); sv[2] = F8(hs.x, 2); sv[3] = F8(hs.x, 3);
    sv[4] = F8(hs.y, 0); sv[5] = F8(hs.y, 1); sv[6] = F8(hs.y, 2); sv[7] = F8(hs.y, 3);
#pragma unroll
    for (int j = 0; j < 8; ++j)
      ps[j] += fmaxf((a[j] + sv[j]) * dsc + bv[j], 0.f);
  }
  if (es == 0) {
#pragma unroll
    for (int j = 0; j < 8; ++j) red[wib][ch * 8 + j] = ps[j];
  }
  __syncthreads();
  if (threadIdx.x < 64) {
    int f = threadIdx.x;
    float sum = red[0][f] + red[1][f] + red[2][f] + red[3][f];
    int b = (blockIdx.x * 16) >> 11;
    atomicAdd(&pool[b * 64 + f], sum);
  }
}

// ---------------- classifier: out[b] = (pool[b]/2048) @ cls_w + cls_b
__global__ __launch_bounds__(64) void classify(const float* __restrict__ pool,
    const float* __restrict__ cw, const float* __restrict__ cb,
    float* __restrict__ out) {
  __shared__ float pl[64];
  int b = blockIdx.x;
  int t = threadIdx.x;
  pl[t] = pool[b * 64 + t] * (1.0f / (float)T2);
  __syncthreads();
  if (t < NOUT) {
    float a = cb[t];
#pragma unroll
    for (int k = 0; k < 64; ++k) a += pl[k] * cw[k * NOUT + t];
    out[b * NOUT + t] = a;
  }
}

extern "C" void kernel_launch(void* const* d_in, const int* in_sizes, int n_in,
                              void* d_out, int out_size, void* d_ws, size_t ws_size,
                              hipStream_t stream) {
  const float* x    = (const float*)d_in[0];
  const int*   ei   = (const int*)d_in[1];
  const float* c1w  = (const float*)d_in[2];
  const float* c1b  = (const float*)d_in[3];
  const float* c2w  = (const float*)d_in[4];
  const float* c2b  = (const float*)d_in[5];
  const float* g1w  = (const float*)d_in[6];
  const float* g1b  = (const float*)d_in[7];
  const float* g2w  = (const float*)d_in[8];
  const float* g2b  = (const float*)d_in[9];
  const float* cw   = (const float*)d_in[10];
  const float* cb   = (const float*)d_in[11];
  float* out = (float*)d_out;
  int E = in_sizes[1] / 2;
  const int N = N_NODES;

  // workspace layout (bytes)
  char* ws = (char*)d_ws;
  int*           gpairs = (int*)(ws);                      //  9,437,184 (packed 4B)
  int*           ebuf   = (int*)(ws + 9437184);            //  9,437,184
  int*           rcnt   = (int*)(ws + 18874368);           //      4,096
  int*           estart = (int*)(ws + 18878464);           //    524,288
  int*           ecnt   = (int*)(ws + 19402752);           //    524,288
  float*         dis    = (float*)(ws + 19927040);         //    524,288
  float*         pool   = (float*)(ws + 20451328);         //     16,384
  unsigned char* xw     = (unsigned char*)(ws + 20467712); //  8,388,608 (fp8)
  unsigned char* xw2    = (unsigned char*)(ws + 28856320); //  8,388,608 (fp8)
  __fp16*        h1     = (__fp16*)(ws + 37244928);        //  8,388,608 (fp16)

  hipMemsetAsync(rcnt, 0, NCB * sizeof(int), stream);
  hipMemsetAsync(pool, 0, BATCH * HID * sizeof(float), stream);

  conv1_kernel<<<dim3(BATCH * 16), dim3(256), 0, stream>>>(x, c1w, c1b, h1);
  partition_pairs<<<dim3((E + PC_EDGES - 1) / PC_EDGES), dim3(256), 0, stream>>>(ei, E, rcnt, gpairs);
  build_csr<<<dim3(NCB), dim3(512), 0, stream>>>(gpairs, rcnt, ebuf, estart, ecnt, dis);

  conv2_gemm1<<<dim3(BATCH * 8), dim3(256), 0, stream>>>(h1, c2w, c2b, g1w, dis, xw);
  agg1_gemm2<<<dim3(N / 16), dim3(256), 0, stream>>>(xw, ebuf, estart, ecnt, dis, g1b, g2w, xw2, N);
  gcn_aggregate_pool<<<dim3(N / 16), dim3(256), 0, stream>>>(xw2, ebuf, estart, ecnt, dis, g2b, pool, N);

  classify<<<dim3(BATCH), dim3(64), 0, stream>>>(pool, cw, cb, out);
}